// Round 1
// baseline (2172.319 us; speedup 1.0000x reference)
//
#include <hip/hip_runtime.h>
#include <math.h>

#define N   50000
#define E   800000
#define F   128
#define DIM 128
#define NF  4
#define ND  32
#define NL  3
#define NC  10
#define G   256
#define TILE 32

__device__ __forceinline__ float sigm(float v) { return 1.0f / (1.0f + __expf(-v)); }

// vl[f][k] = sum_j lin0_W[f][k][j] * att_W[f][j]      (Wl part)
// vr[f][k] = sum_j lin0_W[f][k][j] * att_W[f][DIM+j]  (Wr part)
// cc[f]    = att_b[f] + b.Wl + b.Wr
__global__ void prep_kernel(const float* __restrict__ lin0_W, const float* __restrict__ lin0_b,
                            const float* __restrict__ att_W, const float* __restrict__ att_b,
                            float* __restrict__ vl, float* __restrict__ vr, float* __restrict__ cc) {
    int t = blockIdx.x * blockDim.x + threadIdx.x;
    if (t < NF * F) {
        int f = t >> 7, k = t & 127;
        const float* W  = lin0_W + (size_t)f * F * DIM + (size_t)k * DIM;
        const float* wl = att_W + f * 2 * DIM;
        const float* wr = wl + DIM;
        float sl = 0.f, sr = 0.f;
        for (int j = 0; j < DIM; ++j) { sl += W[j] * wl[j]; sr += W[j] * wr[j]; }
        vl[t] = sl; vr[t] = sr;
    }
    if (t < NF) {
        const float* b  = lin0_b + t * DIM;
        const float* wl = att_W + t * 2 * DIM;
        const float* wr = wl + DIM;
        float s = att_b[t];
        for (int j = 0; j < DIM; ++j) s += b[j] * wl[j] + b[j] * wr[j];
        cc[t] = s;
    }
}

// one block (128 thr) per node: out0 = x@enc_W + enc_b ; al/ar scalars
__global__ void encode_kernel(const float* __restrict__ x, const float* __restrict__ enc_W,
                              const float* __restrict__ enc_b,
                              const float* __restrict__ vl, const float* __restrict__ vr,
                              float* __restrict__ out, float* __restrict__ alr) {
    __shared__ float xs[F];
    int n = blockIdx.x;
    int c = threadIdx.x;                 // 0..127
    xs[c] = x[(size_t)n * F + c];
    __syncthreads();
    int f = c >> 5, d = c & 31;
    const float* Wc = enc_W + (size_t)f * F * ND + d;   // [k] stride ND
    float acc = enc_b[f * ND + d];
    #pragma unroll 8
    for (int k = 0; k < F; ++k) acc += xs[k] * Wc[(size_t)k * ND];
    out[(size_t)n * DIM + c] = acc;
    if (c < 8) {                         // c = 0..3 -> al[f], 4..7 -> ar[f]
        int ff = c & 3;
        const float* v = ((c >= 4) ? vr : vl) + ff * F;
        float s = 0.f;
        for (int k = 0; k < F; ++k) s += xs[k] * v[k];
        alr[(size_t)n * 8 + c] = s;
    }
}

__global__ void att_kernel(const int* __restrict__ ei, const float* __restrict__ alr,
                           const float* __restrict__ cc, float* __restrict__ atts) {
    int e = blockIdx.x * blockDim.x + threadIdx.x;
    if (e >= E) return;
    int s = ei[e];
    int d = ei[E + e];
    float4 al = *(const float4*)(alr + (size_t)s * 8);
    float4 ar = *(const float4*)(alr + (size_t)d * 8 + 4);
    atts[0 * (size_t)E + e] = sigm(6.f * (al.x + ar.x + cc[0]));
    atts[1 * (size_t)E + e] = sigm(6.f * (al.y + ar.y + cc[1]));
    atts[2 * (size_t)E + e] = sigm(6.f * (al.z + ar.z + cc[2]));
    atts[3 * (size_t)E + e] = sigm(6.f * (al.w + ar.w + cc[3]));
}

// 128 consecutive threads handle one edge's 128 channels (all 4 groups)
__global__ void scatter_kernel(const int* __restrict__ ei, const float* __restrict__ atts,
                               const float* __restrict__ out, float* __restrict__ agg) {
    long long t = (long long)blockIdx.x * 256 + threadIdx.x;
    int e = (int)(t >> 7);
    int c = (int)(t & 127);
    if (e >= E) return;
    int s = ei[e];
    int d = ei[E + e];
    float a = atts[(size_t)(c >> 5) * E + e];
    float v = a * out[(size_t)s * DIM + c];
    atomicAdd(agg + (size_t)d * DIM + c, v);
}

// conv + GRU fused, one block = TILE nodes for one group f
__global__ __launch_bounds__(256) void update_kernel(
        const float* __restrict__ agg, float* __restrict__ out,
        const float* __restrict__ Wrel, const float* __restrict__ brel,
        const float* __restrict__ Wroot,
        const float* __restrict__ Wih, const float* __restrict__ Whh,
        const float* __restrict__ bih, const float* __restrict__ bhh, int l) {
    __shared__ float sWrel[ND * ND], sWroot[ND * ND];
    __shared__ float sWihT[ND * 97], sWhhT[ND * 97];   // [d][j], pad 97 vs 96
    __shared__ float sbrel[ND], sbih[3 * ND], sbhh[3 * ND];
    __shared__ float sAgg[TILE][ND], sOut[TILE][ND], sM[TILE][ND];
    int f = blockIdx.y;
    int tid = threadIdx.x;
    const float* wrel  = Wrel  + (size_t)(f * NL + l) * ND * ND;
    const float* wroot = Wroot + (size_t)(f * NL + l) * ND * ND;
    for (int i = tid; i < ND * ND; i += 256) { sWrel[i] = wrel[i]; sWroot[i] = wroot[i]; }
    const float* wih = Wih + (size_t)f * 3 * ND * ND;  // [j][d]
    const float* whh = Whh + (size_t)f * 3 * ND * ND;
    for (int i = tid; i < 3 * ND * ND; i += 256) {
        int j = i >> 5, d = i & 31;
        sWihT[d * 97 + j] = wih[i];
        sWhhT[d * 97 + j] = whh[i];
    }
    if (tid < ND) sbrel[tid] = brel[(size_t)(f * NL + l) * ND + tid];
    if (tid < 3 * ND) { sbih[tid] = bih[f * 3 * ND + tid]; sbhh[tid] = bhh[f * 3 * ND + tid]; }
    int node0 = blockIdx.x * TILE;
    for (int i = tid; i < TILE * ND; i += 256) {
        int ni = i >> 5, d = i & 31;
        int n = node0 + ni;
        float av = 0.f, ov = 0.f;
        if (n < N) {
            av = agg[(size_t)n * DIM + f * ND + d];
            ov = out[(size_t)n * DIM + f * ND + d];
        }
        sAgg[ni][d] = av; sOut[ni][d] = ov;
    }
    __syncthreads();
    int di = tid & 31;
    int i0 = tid >> 5;                   // 0..7
    for (int ni = i0; ni < TILE; ni += 8) {
        float acc = sbrel[di];
        #pragma unroll
        for (int k = 0; k < ND; ++k)
            acc += sAgg[ni][k] * sWrel[k * ND + di] + sOut[ni][k] * sWroot[k * ND + di];
        sM[ni][di] = fmaxf(acc, 0.f);
    }
    __syncthreads();
    for (int ni = i0; ni < TILE; ni += 8) {
        float gi0 = sbih[di], gi1 = sbih[32 + di], gi2 = sbih[64 + di];
        float gh0 = sbhh[di], gh1 = sbhh[32 + di], gh2 = sbhh[64 + di];
        #pragma unroll
        for (int d = 0; d < ND; ++d) {
            float mv = sM[ni][d], hv = sOut[ni][d];
            const float* wi = &sWihT[d * 97];
            const float* wh = &sWhhT[d * 97];
            gi0 += mv * wi[di];      gi1 += mv * wi[32 + di];  gi2 += mv * wi[64 + di];
            gh0 += hv * wh[di];      gh1 += hv * wh[32 + di];  gh2 += hv * wh[64 + di];
        }
        float r  = sigm(gi0 + gh0);
        float z  = sigm(gi1 + gh1);
        float nn = tanhf(gi2 + r * gh2);
        float hv = sOut[ni][di];
        float nh = (1.f - z) * nn + z * hv;
        int n = node0 + ni;
        if (n < N) out[(size_t)n * DIM + f * ND + di] = nh;
    }
}

__global__ void count_kernel(const int* __restrict__ batch, float* __restrict__ counts) {
    int n = blockIdx.x * blockDim.x + threadIdx.x;
    if (n < N) atomicAdd(&counts[batch[n]], 1.0f);
}

__global__ void pool_kernel(const int* __restrict__ batch, const float* __restrict__ st,
                            float* __restrict__ pooled) {
    long long t = (long long)blockIdx.x * 256 + threadIdx.x;
    int n = (int)(t >> 7);
    int c = (int)(t & 127);
    if (n >= N) return;
    int g = batch[n];
    atomicAdd(&pooled[(size_t)g * DIM + c], st[(size_t)n * DIM + c]);
}

__global__ void norm_kernel(float* __restrict__ pooled, const float* __restrict__ counts,
                            float* __restrict__ outsout) {
    int t = blockIdx.x * blockDim.x + threadIdx.x;
    if (t >= G * DIM) return;
    int g = t >> 7, c = t & 127;
    float val = pooled[t] / fmaxf(counts[g], 1.0f);
    pooled[t] = val;
    int f = c >> 5, d = c & 31;
    outsout[(size_t)f * G * ND + g * ND + d] = val;
}

__global__ void mlp_kernel(const float* __restrict__ pooled,
                           const float* __restrict__ fc1_W, const float* __restrict__ fc1_b,
                           const float* __restrict__ fc2_W, const float* __restrict__ fc2_b,
                           float* __restrict__ pred) {
    __shared__ float row[DIM], hid[DIM];
    int g = blockIdx.x, c = threadIdx.x;
    row[c] = pooled[(size_t)g * DIM + c];
    __syncthreads();
    float acc = fc1_b[c];
    #pragma unroll 8
    for (int k = 0; k < DIM; ++k) acc += row[k] * fc1_W[k * DIM + c];
    hid[c] = fmaxf(acc, 0.f);
    __syncthreads();
    if (c < NC) {
        float p = fc2_b[c];
        for (int k = 0; k < DIM; ++k) p += hid[k] * fc2_W[k * NC + c];
        pred[(size_t)g * NC + c] = p;
    }
}

extern "C" void kernel_launch(void* const* d_in, const int* in_sizes, int n_in,
                              void* d_out, int out_size, void* d_ws, size_t ws_size,
                              hipStream_t stream) {
    const float* x         = (const float*)d_in[0];
    const int*   ei        = (const int*)  d_in[1];
    const int*   batch     = (const int*)  d_in[2];
    const float* lin0_W    = (const float*)d_in[3];
    const float* lin0_b    = (const float*)d_in[4];
    const float* att_W     = (const float*)d_in[5];
    const float* att_b     = (const float*)d_in[6];
    const float* enc_W     = (const float*)d_in[7];
    const float* enc_b     = (const float*)d_in[8];
    const float* conv_Wrel = (const float*)d_in[9];
    const float* conv_brel = (const float*)d_in[10];
    const float* conv_Wroot= (const float*)d_in[11];
    const float* gru_Wih   = (const float*)d_in[12];
    const float* gru_Whh   = (const float*)d_in[13];
    const float* gru_bih   = (const float*)d_in[14];
    const float* gru_bhh   = (const float*)d_in[15];
    const float* fc1_W     = (const float*)d_in[16];
    const float* fc1_b     = (const float*)d_in[17];
    const float* fc2_W     = (const float*)d_in[18];
    const float* fc2_b     = (const float*)d_in[19];

    float* outp    = (float*)d_out;
    float* pred    = outp;                       // G*NC
    float* atts    = outp + G * NC;              // NF*E
    float* outsout = atts + (size_t)NF * E;      // NF*G*ND

    float* ws     = (float*)d_ws;
    float* st     = ws;                          // N*DIM
    float* agg    = st  + (size_t)N * DIM;       // N*DIM
    float* alr    = agg + (size_t)N * DIM;       // N*8
    float* vl     = alr + (size_t)N * 8;         // NF*F
    float* vr     = vl + NF * F;                 // NF*F
    float* cc     = vr + NF * F;                 // NF
    float* pooled = cc + NF;                     // G*DIM
    float* counts = pooled + G * DIM;            // G

    prep_kernel<<<2, 256, 0, stream>>>(lin0_W, lin0_b, att_W, att_b, vl, vr, cc);
    encode_kernel<<<N, 128, 0, stream>>>(x, enc_W, enc_b, vl, vr, st, alr);
    att_kernel<<<(E + 255) / 256, 256, 0, stream>>>(ei, alr, cc, atts);
    for (int l = 0; l < NL; ++l) {
        hipMemsetAsync(agg, 0, (size_t)N * DIM * sizeof(float), stream);
        scatter_kernel<<<(int)(((long long)E * 128) / 256), 256, 0, stream>>>(ei, atts, st, agg);
        dim3 gupd((N + TILE - 1) / TILE, NF);
        update_kernel<<<gupd, 256, 0, stream>>>(agg, st, conv_Wrel, conv_brel, conv_Wroot,
                                                gru_Wih, gru_Whh, gru_bih, gru_bhh, l);
    }
    hipMemsetAsync(pooled, 0, (G * DIM + G) * sizeof(float), stream);
    count_kernel<<<(N + 255) / 256, 256, 0, stream>>>(batch, counts);
    pool_kernel<<<(N * DIM) / 256, 256, 0, stream>>>(batch, st, pooled);
    norm_kernel<<<(G * DIM) / 256, 256, 0, stream>>>(pooled, counts, outsout);
    mlp_kernel<<<G, DIM, 0, stream>>>(pooled, fc1_W, fc1_b, fc2_W, fc2_b, pred);
}

// Round 2
// 1216.725 us; speedup vs baseline: 1.7854x; 1.7854x over previous
//
#include <hip/hip_runtime.h>
#include <math.h>

#define N   50000
#define E   800000
#define F   128
#define DIM 128
#define NF  4
#define ND  32
#define NL  3
#define NC  10
#define G   256
#define UT  64     // nodes per update block
#define NB  196    // ceil(N/256) scan blocks

__device__ __forceinline__ float sigm(float v) { return 1.0f / (1.0f + __expf(-v)); }

// vl[f][k] = sum_j lin0_W[f][k][j]*att_W[f][j] ; vr likewise with Wr; cc[f] = att_b + b.(Wl+Wr)
__global__ void prep_kernel(const float* __restrict__ lin0_W, const float* __restrict__ lin0_b,
                            const float* __restrict__ att_W, const float* __restrict__ att_b,
                            float* __restrict__ vl, float* __restrict__ vr, float* __restrict__ cc) {
    int t = blockIdx.x * blockDim.x + threadIdx.x;
    if (t < NF * F) {
        int f = t >> 7, k = t & 127;
        const float* W  = lin0_W + (size_t)f * F * DIM + (size_t)k * DIM;
        const float* wl = att_W + f * 2 * DIM;
        const float* wr = wl + DIM;
        float sl = 0.f, sr = 0.f;
        for (int j = 0; j < DIM; ++j) { sl += W[j] * wl[j]; sr += W[j] * wr[j]; }
        vl[t] = sl; vr[t] = sr;
    }
    if (t < NF) {
        const float* b  = lin0_b + t * DIM;
        const float* wl = att_W + t * 2 * DIM;
        const float* wr = wl + DIM;
        float s = att_b[t];
        for (int j = 0; j < DIM; ++j) s += b[j] * (wl[j] + wr[j]);
        cc[t] = s;
    }
}

// one block (128 thr) per node: st = x@enc_W + enc_b ; alr = 8 attention scalars
__global__ void encode_kernel(const float* __restrict__ x, const float* __restrict__ enc_W,
                              const float* __restrict__ enc_b,
                              const float* __restrict__ vl, const float* __restrict__ vr,
                              float* __restrict__ out, float* __restrict__ alr) {
    __shared__ float xs[F];
    int n = blockIdx.x;
    int c = threadIdx.x;
    xs[c] = x[(size_t)n * F + c];
    __syncthreads();
    int f = c >> 5, d = c & 31;
    const float* Wc = enc_W + (size_t)f * F * ND + d;
    float acc = enc_b[f * ND + d];
    #pragma unroll 8
    for (int k = 0; k < F; ++k) acc += xs[k] * Wc[(size_t)k * ND];
    out[(size_t)n * DIM + c] = acc;
    if (c < 8) {
        int ff = c & 3;
        const float* v = ((c >= 4) ? vr : vl) + ff * F;
        float s = 0.f;
        for (int k = 0; k < F; ++k) s += xs[k] * v[k];
        alr[(size_t)n * 8 + c] = s;
    }
}

__global__ void att_kernel(const int* __restrict__ ei, const float* __restrict__ alr,
                           const float* __restrict__ cc, float* __restrict__ atts) {
    int e = blockIdx.x * blockDim.x + threadIdx.x;
    if (e >= E) return;
    int s = ei[e];
    int d = ei[E + e];
    float4 al = *(const float4*)(alr + (size_t)s * 8);
    float4 ar = *(const float4*)(alr + (size_t)d * 8 + 4);
    atts[0 * (size_t)E + e] = sigm(6.f * (al.x + ar.x + cc[0]));
    atts[1 * (size_t)E + e] = sigm(6.f * (al.y + ar.y + cc[1]));
    atts[2 * (size_t)E + e] = sigm(6.f * (al.z + ar.z + cc[2]));
    atts[3 * (size_t)E + e] = sigm(6.f * (al.w + ar.w + cc[3]));
}

// ---------------- CSR build ----------------
__global__ void hist_kernel(const int* __restrict__ ei, int* __restrict__ deg) {
    int e = blockIdx.x * 256 + threadIdx.x;
    if (e < E) atomicAdd(&deg[ei[E + e]], 1);
}

__global__ void scan1_kernel(const int* __restrict__ deg, int* __restrict__ rowp,
                             int* __restrict__ bsum) {
    __shared__ int sh[256];
    int i = blockIdx.x * 256 + threadIdx.x;
    int v = (i < N) ? deg[i] : 0;
    sh[threadIdx.x] = v;
    __syncthreads();
    for (int off = 1; off < 256; off <<= 1) {
        int t = 0;
        if ((int)threadIdx.x >= off) t = sh[threadIdx.x - off];
        __syncthreads();
        sh[threadIdx.x] += t;
        __syncthreads();
    }
    if (i < N) rowp[i] = sh[threadIdx.x] - v;
    if (threadIdx.x == 255) bsum[blockIdx.x] = sh[255];
}

__global__ void scan2_kernel(int* __restrict__ bsum) {
    __shared__ int sh[256];
    int v = ((int)threadIdx.x < NB) ? bsum[threadIdx.x] : 0;
    sh[threadIdx.x] = v;
    __syncthreads();
    for (int off = 1; off < 256; off <<= 1) {
        int t = 0;
        if ((int)threadIdx.x >= off) t = sh[threadIdx.x - off];
        __syncthreads();
        sh[threadIdx.x] += t;
        __syncthreads();
    }
    if ((int)threadIdx.x < NB) bsum[threadIdx.x] = sh[threadIdx.x] - v;
}

__global__ void scan3_kernel(int* __restrict__ rowp, const int* __restrict__ bsum) {
    int i = blockIdx.x * 256 + threadIdx.x;
    if (i < N) rowp[i] += bsum[i >> 8];
}

__global__ void fill_kernel(const int* __restrict__ ei, const float* __restrict__ atts,
                            const int* __restrict__ rowp, int* __restrict__ cnt,
                            int* __restrict__ esrc, float* __restrict__ attp) {
    int e = blockIdx.x * 256 + threadIdx.x;
    if (e >= E) return;
    int d = ei[E + e];
    int slot = rowp[d] + atomicAdd(&cnt[d], 1);
    esrc[slot] = ei[e];
    attp[slot]                = atts[e];
    attp[(size_t)E + slot]    = atts[(size_t)E + e];
    attp[2 * (size_t)E + slot] = atts[2 * (size_t)E + e];
    attp[3 * (size_t)E + slot] = atts[3 * (size_t)E + e];
}

// ---------------- gather (replaces atomic scatter) ----------------
// 32 threads per node, float4 channels; 8 nodes per 256-thr block
__global__ void gather_kernel(const int* __restrict__ esrc, const float* __restrict__ attp,
                              const int* __restrict__ rowp, const int* __restrict__ deg,
                              const float* __restrict__ out, float* __restrict__ agg) {
    int t = blockIdx.x * 256 + threadIdx.x;
    int n = t >> 5;
    if (n >= N) return;
    int c4 = t & 31;                 // float4 lane: channels 4*c4..4*c4+3
    int f = c4 >> 3;
    int beg = rowp[n];
    int cnt = deg[n];
    const float* ap = attp + (size_t)f * E + beg;
    const int*   sp = esrc + beg;
    float4 acc = make_float4(0.f, 0.f, 0.f, 0.f);
    for (int i = 0; i < cnt; ++i) {
        int s = sp[i];
        float a = ap[i];
        float4 v = *(const float4*)(out + (size_t)s * DIM + c4 * 4);
        acc.x += a * v.x; acc.y += a * v.y; acc.z += a * v.z; acc.w += a * v.w;
    }
    *(float4*)(agg + (size_t)n * DIM + c4 * 4) = acc;
}

// ---------------- conv + GRU: register weights, LDS-broadcast activations ----------------
__global__ __launch_bounds__(256, 2) void update_kernel(
        const float* __restrict__ agg, float* __restrict__ out,
        const float* __restrict__ Wrel, const float* __restrict__ brel,
        const float* __restrict__ Wroot,
        const float* __restrict__ Wih, const float* __restrict__ Whh,
        const float* __restrict__ bih, const float* __restrict__ bhh, int l) {
    __shared__ float sWrel[32 * 33], sWroot[32 * 33];
    __shared__ float sWih[96 * 33], sWhh[96 * 33];
    __shared__ float sbrel[32], sbih[96], sbhh[96];
    __shared__ float sAgg[UT * 32], sOut[UT * 32], sM[UT * 32];
    int f = blockIdx.y;
    int tid = threadIdx.x;
    const float* wrelg  = Wrel  + (size_t)(f * NL + l) * 1024;
    const float* wrootg = Wroot + (size_t)(f * NL + l) * 1024;
    for (int i = tid; i < 1024; i += 256) {
        int k = i >> 5, d = i & 31;
        sWrel[k * 33 + d] = wrelg[i];
        sWroot[k * 33 + d] = wrootg[i];
    }
    const float* wihg = Wih + (size_t)f * 3072;
    const float* whhg = Whh + (size_t)f * 3072;
    for (int i = tid; i < 3072; i += 256) {
        int j = i >> 5, k = i & 31;
        sWih[j * 33 + k] = wihg[i];
        sWhh[j * 33 + k] = whhg[i];
    }
    if (tid < 32) sbrel[tid] = brel[(size_t)(f * NL + l) * 32 + tid];
    if (tid < 96) { sbih[tid] = bih[f * 96 + tid]; sbhh[tid] = bhh[f * 96 + tid]; }
    int node0 = blockIdx.x * UT;
    for (int i = tid; i < UT * 32; i += 256) {
        int ni = i >> 5, d = i & 31;
        int n = node0 + ni;
        float av = 0.f, ov = 0.f;
        if (n < N) {
            av = agg[(size_t)n * DIM + f * ND + d];
            ov = out[(size_t)n * DIM + f * ND + d];
        }
        sAgg[i] = av; sOut[i] = ov;
    }
    __syncthreads();
    int di = tid & 31, sg = tid >> 5;    // 8 subgroups of 32 lanes
    // --- conv: m = relu(agg@Wrel + out@Wroot + brel) ---
    {
        float wr[32], wo[32];
        #pragma unroll
        for (int k = 0; k < 32; ++k) { wr[k] = sWrel[k * 33 + di]; wo[k] = sWroot[k * 33 + di]; }
        float br = sbrel[di];
        for (int ni = sg; ni < UT; ni += 8) {
            const float4* a4 = (const float4*)&sAgg[ni * 32];
            const float4* o4 = (const float4*)&sOut[ni * 32];
            float acc = br;
            #pragma unroll
            for (int k4 = 0; k4 < 8; ++k4) {
                float4 a = a4[k4], o = o4[k4];
                int k = k4 * 4;
                acc += a.x * wr[k] + a.y * wr[k + 1] + a.z * wr[k + 2] + a.w * wr[k + 3];
                acc += o.x * wo[k] + o.y * wo[k + 1] + o.z * wo[k + 2] + o.w * wo[k + 3];
            }
            sM[ni * 32 + di] = fmaxf(acc, 0.f);
        }
    }
    __syncthreads();
    // --- GRU ---
    float wi0[32], wi1[32], wi2[32], wh0[32], wh1[32], wh2[32];
    #pragma unroll
    for (int k = 0; k < 32; ++k) {
        wi0[k] = sWih[di * 33 + k];
        wi1[k] = sWih[(32 + di) * 33 + k];
        wi2[k] = sWih[(64 + di) * 33 + k];
        wh0[k] = sWhh[di * 33 + k];
        wh1[k] = sWhh[(32 + di) * 33 + k];
        wh2[k] = sWhh[(64 + di) * 33 + k];
    }
    float bi0 = sbih[di], bi1 = sbih[32 + di], bi2 = sbih[64 + di];
    float bh0 = sbhh[di], bh1 = sbhh[32 + di], bh2 = sbhh[64 + di];
    for (int ni = sg; ni < UT; ni += 8) {
        const float4* m4 = (const float4*)&sM[ni * 32];
        const float4* h4 = (const float4*)&sOut[ni * 32];
        float gi0 = bi0, gi1 = bi1, gi2 = bi2;
        float gh0 = bh0, gh1 = bh1, gh2 = bh2;
        #pragma unroll
        for (int k4 = 0; k4 < 8; ++k4) {
            float4 m = m4[k4], h = h4[k4];
            int k = k4 * 4;
            gi0 += m.x * wi0[k] + m.y * wi0[k + 1] + m.z * wi0[k + 2] + m.w * wi0[k + 3];
            gi1 += m.x * wi1[k] + m.y * wi1[k + 1] + m.z * wi1[k + 2] + m.w * wi1[k + 3];
            gi2 += m.x * wi2[k] + m.y * wi2[k + 1] + m.z * wi2[k + 2] + m.w * wi2[k + 3];
            gh0 += h.x * wh0[k] + h.y * wh0[k + 1] + h.z * wh0[k + 2] + h.w * wh0[k + 3];
            gh1 += h.x * wh1[k] + h.y * wh1[k + 1] + h.z * wh1[k + 2] + h.w * wh1[k + 3];
            gh2 += h.x * wh2[k] + h.y * wh2[k + 1] + h.z * wh2[k + 2] + h.w * wh2[k + 3];
        }
        float r = sigm(gi0 + gh0);
        float z = sigm(gi1 + gh1);
        float x2 = gi2 + r * gh2;
        float nn = 2.f * sigm(2.f * x2) - 1.f;   // tanh
        float hv = sOut[ni * 32 + di];
        float nh = (1.f - z) * nn + z * hv;
        int n = node0 + ni;
        if (n < N) out[(size_t)n * DIM + f * ND + di] = nh;
    }
}

// ---------------- pooling (sorted batch -> segmented reduction) ----------------
__global__ void ghist_kernel(const int* __restrict__ batch, int* __restrict__ gcnt) {
    int n = blockIdx.x * 256 + threadIdx.x;
    if (n < N) atomicAdd(&gcnt[batch[n]], 1);
}

__global__ void gscan_kernel(const int* __restrict__ gcnt, int* __restrict__ goff) {
    __shared__ int sh[256];
    int v = gcnt[threadIdx.x];
    sh[threadIdx.x] = v;
    __syncthreads();
    for (int off = 1; off < 256; off <<= 1) {
        int t = 0;
        if ((int)threadIdx.x >= off) t = sh[threadIdx.x - off];
        __syncthreads();
        sh[threadIdx.x] += t;
        __syncthreads();
    }
    goff[threadIdx.x] = sh[threadIdx.x] - v;
}

__global__ void pool_kernel(const float* __restrict__ st, const int* __restrict__ goff,
                            const int* __restrict__ gcnt, float* __restrict__ pooled,
                            float* __restrict__ outsout) {
    __shared__ float acc2[128];
    int g = blockIdx.x;
    int c = threadIdx.x & 127;
    int half = threadIdx.x >> 7;
    int beg = goff[g], cnt = gcnt[g];
    float acc = 0.f;
    for (int i = half; i < cnt; i += 2) acc += st[(size_t)(beg + i) * DIM + c];
    if (half == 1) acc2[c] = acc;
    __syncthreads();
    if (half == 0) {
        float tot = acc + acc2[c];
        float val = tot / fmaxf((float)cnt, 1.0f);
        pooled[g * DIM + c] = val;
        int f = c >> 5, d = c & 31;
        outsout[((size_t)f * G + g) * ND + d] = val;
    }
}

__global__ void mlp_kernel(const float* __restrict__ pooled,
                           const float* __restrict__ fc1_W, const float* __restrict__ fc1_b,
                           const float* __restrict__ fc2_W, const float* __restrict__ fc2_b,
                           float* __restrict__ pred) {
    __shared__ float row[DIM], hid[DIM];
    int g = blockIdx.x, c = threadIdx.x;
    row[c] = pooled[(size_t)g * DIM + c];
    __syncthreads();
    float acc = fc1_b[c];
    #pragma unroll 8
    for (int k = 0; k < DIM; ++k) acc += row[k] * fc1_W[k * DIM + c];
    hid[c] = fmaxf(acc, 0.f);
    __syncthreads();
    if (c < NC) {
        float p = fc2_b[c];
        for (int k = 0; k < DIM; ++k) p += hid[k] * fc2_W[k * NC + c];
        pred[(size_t)g * NC + c] = p;
    }
}

extern "C" void kernel_launch(void* const* d_in, const int* in_sizes, int n_in,
                              void* d_out, int out_size, void* d_ws, size_t ws_size,
                              hipStream_t stream) {
    const float* x         = (const float*)d_in[0];
    const int*   ei        = (const int*)  d_in[1];
    const int*   batch     = (const int*)  d_in[2];
    const float* lin0_W    = (const float*)d_in[3];
    const float* lin0_b    = (const float*)d_in[4];
    const float* att_W     = (const float*)d_in[5];
    const float* att_b     = (const float*)d_in[6];
    const float* enc_W     = (const float*)d_in[7];
    const float* enc_b     = (const float*)d_in[8];
    const float* conv_Wrel = (const float*)d_in[9];
    const float* conv_brel = (const float*)d_in[10];
    const float* conv_Wroot= (const float*)d_in[11];
    const float* gru_Wih   = (const float*)d_in[12];
    const float* gru_Whh   = (const float*)d_in[13];
    const float* gru_bih   = (const float*)d_in[14];
    const float* gru_bhh   = (const float*)d_in[15];
    const float* fc1_W     = (const float*)d_in[16];
    const float* fc1_b     = (const float*)d_in[17];
    const float* fc2_W     = (const float*)d_in[18];
    const float* fc2_b     = (const float*)d_in[19];

    float* outp    = (float*)d_out;
    float* pred    = outp;                       // G*NC
    float* atts    = outp + G * NC;              // NF*E
    float* outsout = atts + (size_t)NF * E;      // NF*G*ND

    float* fp     = (float*)d_ws;
    float* st     = fp;                   fp += (size_t)N * DIM;
    float* agg    = fp;                   fp += (size_t)N * DIM;
    float* alr    = fp;                   fp += (size_t)N * 8;
    float* vl     = fp;                   fp += NF * F;
    float* vr     = fp;                   fp += NF * F;
    float* cc     = fp;                   fp += 4;
    float* pooled = fp;                   fp += G * DIM;
    float* attp   = fp;                   fp += (size_t)NF * E;
    int* ip    = (int*)fp;
    int* deg   = ip;                      ip += N;
    int* cnt   = ip;                      ip += N;   // deg & cnt adjacent -> one memset
    int* rowp  = ip;                      ip += N;
    int* bsum  = ip;                      ip += 256;
    int* gcnt  = ip;                      ip += G;
    int* goff  = ip;                      ip += G;
    int* esrc  = ip;                      ip += E;

    hipMemsetAsync(deg, 0, (size_t)(2 * N) * sizeof(int), stream);
    hipMemsetAsync(gcnt, 0, (size_t)G * sizeof(int), stream);

    prep_kernel<<<2, 256, 0, stream>>>(lin0_W, lin0_b, att_W, att_b, vl, vr, cc);
    encode_kernel<<<N, 128, 0, stream>>>(x, enc_W, enc_b, vl, vr, st, alr);
    att_kernel<<<(E + 255) / 256, 256, 0, stream>>>(ei, alr, cc, atts);

    // CSR build (once; reused by all 3 layers)
    hist_kernel<<<(E + 255) / 256, 256, 0, stream>>>(ei, deg);
    scan1_kernel<<<NB, 256, 0, stream>>>(deg, rowp, bsum);
    scan2_kernel<<<1, 256, 0, stream>>>(bsum);
    scan3_kernel<<<NB, 256, 0, stream>>>(rowp, bsum);
    fill_kernel<<<(E + 255) / 256, 256, 0, stream>>>(ei, atts, rowp, cnt, esrc, attp);

    for (int l = 0; l < NL; ++l) {
        gather_kernel<<<(N * 32 + 255) / 256, 256, 0, stream>>>(esrc, attp, rowp, deg, st, agg);
        dim3 gupd((N + UT - 1) / UT, NF);
        update_kernel<<<gupd, 256, 0, stream>>>(agg, st, conv_Wrel, conv_brel, conv_Wroot,
                                                gru_Wih, gru_Whh, gru_bih, gru_bhh, l);
    }

    ghist_kernel<<<(N + 255) / 256, 256, 0, stream>>>(batch, gcnt);
    gscan_kernel<<<1, 256, 0, stream>>>(gcnt, goff);
    pool_kernel<<<G, 256, 0, stream>>>(st, goff, gcnt, pooled, outsout);
    mlp_kernel<<<G, DIM, 0, stream>>>(pooled, fc1_W, fc1_b, fc2_W, fc2_b, pred);
}

// Round 3
// 860.648 us; speedup vs baseline: 2.5241x; 1.4137x over previous
//
#include <hip/hip_runtime.h>
#include <math.h>

#define N   50000
#define E   800000
#define F   128
#define DIM 128
#define NF  4
#define ND  32
#define NL  3
#define NC  10
#define G   256
#define NB  196    // ceil(N/256) scan blocks

__device__ __forceinline__ float sigm(float v) { return 1.0f / (1.0f + __expf(-v)); }

// vl[f][k] = sum_j lin0_W[f][k][j]*att_W[f][j] ; vr likewise with Wr; cc[f] = att_b + b.(Wl+Wr)
__global__ void prep_kernel(const float* __restrict__ lin0_W, const float* __restrict__ lin0_b,
                            const float* __restrict__ att_W, const float* __restrict__ att_b,
                            float* __restrict__ vl, float* __restrict__ vr, float* __restrict__ cc) {
    int t = blockIdx.x * blockDim.x + threadIdx.x;
    if (t < NF * F) {
        int f = t >> 7, k = t & 127;
        const float* W  = lin0_W + (size_t)f * F * DIM + (size_t)k * DIM;
        const float* wl = att_W + f * 2 * DIM;
        const float* wr = wl + DIM;
        float sl = 0.f, sr = 0.f;
        for (int j = 0; j < DIM; ++j) { sl += W[j] * wl[j]; sr += W[j] * wr[j]; }
        vl[t] = sl; vr[t] = sr;
    }
    if (t < NF) {
        const float* b  = lin0_b + t * DIM;
        const float* wl = att_W + t * 2 * DIM;
        const float* wr = wl + DIM;
        float s = att_b[t];
        for (int j = 0; j < DIM; ++j) s += b[j] * (wl[j] + wr[j]);
        cc[t] = s;
    }
}

// transpose GRU weights: wihT[f][k][j] = Wih[f][j][k]  (rows contiguous in j for s_load)
__global__ void wtrans_kernel(const float* __restrict__ Wih, const float* __restrict__ Whh,
                              float* __restrict__ wihT, float* __restrict__ whhT) {
    int t = blockIdx.x * 256 + threadIdx.x;
    if (t >= NF * 3 * ND * ND) return;
    int f = t / 3072, rem = t % 3072;
    int k = rem / 96, j = rem % 96;
    wihT[t] = Wih[f * 3072 + j * 32 + k];
    whhT[t] = Whh[f * 3072 + j * 32 + k];
}

// lane = node, wave = f. Weights are wave-uniform -> SGPR streamed.
__global__ __launch_bounds__(256) void encode_kernel(
        const float* __restrict__ x, const float* __restrict__ enc_W,
        const float* __restrict__ enc_b,
        const float* __restrict__ vl, const float* __restrict__ vr,
        float* __restrict__ out, float* __restrict__ alr) {
    int tid = threadIdx.x;
    int f = __builtin_amdgcn_readfirstlane(tid >> 6);
    int n = blockIdx.x * 64 + (tid & 63);
    int nc = n < N ? n : N - 1;
    const float* px  = x + (size_t)nc * F;
    const float* wf  = enc_W + (size_t)f * F * ND;
    const float* pvl = vl + f * F;
    const float* pvr = vr + f * F;
    const float* pb  = enc_b + f * ND;
    float acc[32];
    #pragma unroll
    for (int j = 0; j < 32; ++j) acc[j] = pb[j];
    float sl = 0.f, sr = 0.f;
    for (int k4 = 0; k4 < 32; ++k4) {
        float4 xv = *(const float4*)(px + k4 * 4);
        float xs[4] = {xv.x, xv.y, xv.z, xv.w};
        #pragma unroll
        for (int u = 0; u < 4; ++u) {
            int k = k4 * 4 + u;
            float xk = xs[u];
            const float* wrow = wf + k * 32;
            #pragma unroll
            for (int j = 0; j < 32; ++j) acc[j] = fmaf(xk, wrow[j], acc[j]);
            sl = fmaf(xk, pvl[k], sl);
            sr = fmaf(xk, pvr[k], sr);
        }
    }
    if (n < N) {
        float* po = out + (size_t)n * DIM + f * ND;
        #pragma unroll
        for (int q = 0; q < 8; ++q)
            *(float4*)(po + q * 4) = make_float4(acc[4*q], acc[4*q+1], acc[4*q+2], acc[4*q+3]);
        alr[(size_t)n * 8 + f]     = sl;
        alr[(size_t)n * 8 + 4 + f] = sr;
    }
}

__global__ void att_kernel(const int* __restrict__ ei, const float* __restrict__ alr,
                           const float* __restrict__ cc, float* __restrict__ atts) {
    int e = blockIdx.x * blockDim.x + threadIdx.x;
    if (e >= E) return;
    int s = ei[e];
    int d = ei[E + e];
    float4 al = *(const float4*)(alr + (size_t)s * 8);
    float4 ar = *(const float4*)(alr + (size_t)d * 8 + 4);
    atts[0 * (size_t)E + e] = sigm(6.f * (al.x + ar.x + cc[0]));
    atts[1 * (size_t)E + e] = sigm(6.f * (al.y + ar.y + cc[1]));
    atts[2 * (size_t)E + e] = sigm(6.f * (al.z + ar.z + cc[2]));
    atts[3 * (size_t)E + e] = sigm(6.f * (al.w + ar.w + cc[3]));
}

// ---------------- CSR build ----------------
__global__ void hist_kernel(const int* __restrict__ ei, int* __restrict__ deg) {
    int e = blockIdx.x * 256 + threadIdx.x;
    if (e < E) atomicAdd(&deg[ei[E + e]], 1);
}

__global__ void scan1_kernel(const int* __restrict__ deg, int* __restrict__ rowp,
                             int* __restrict__ bsum) {
    __shared__ int sh[256];
    int i = blockIdx.x * 256 + threadIdx.x;
    int v = (i < N) ? deg[i] : 0;
    sh[threadIdx.x] = v;
    __syncthreads();
    for (int off = 1; off < 256; off <<= 1) {
        int t = 0;
        if ((int)threadIdx.x >= off) t = sh[threadIdx.x - off];
        __syncthreads();
        sh[threadIdx.x] += t;
        __syncthreads();
    }
    if (i < N) rowp[i] = sh[threadIdx.x] - v;
    if (threadIdx.x == 255) bsum[blockIdx.x] = sh[255];
}

__global__ void scan2_kernel(int* __restrict__ bsum) {
    __shared__ int sh[256];
    int v = ((int)threadIdx.x < NB) ? bsum[threadIdx.x] : 0;
    sh[threadIdx.x] = v;
    __syncthreads();
    for (int off = 1; off < 256; off <<= 1) {
        int t = 0;
        if ((int)threadIdx.x >= off) t = sh[threadIdx.x - off];
        __syncthreads();
        sh[threadIdx.x] += t;
        __syncthreads();
    }
    if ((int)threadIdx.x < NB) bsum[threadIdx.x] = sh[threadIdx.x] - v;
}

__global__ void scan3_kernel(int* __restrict__ rowp, const int* __restrict__ bsum) {
    int i = blockIdx.x * 256 + threadIdx.x;
    if (i < N) rowp[i] += bsum[i >> 8];
}

__global__ void fill_kernel(const int* __restrict__ ei, const float* __restrict__ atts,
                            const int* __restrict__ rowp, int* __restrict__ cnt,
                            int* __restrict__ esrc, float* __restrict__ attp) {
    int e = blockIdx.x * 256 + threadIdx.x;
    if (e >= E) return;
    int d = ei[E + e];
    int slot = rowp[d] + atomicAdd(&cnt[d], 1);
    esrc[slot] = ei[e];
    attp[slot]                 = atts[e];
    attp[(size_t)E + slot]     = atts[(size_t)E + e];
    attp[2 * (size_t)E + slot] = atts[2 * (size_t)E + e];
    attp[3 * (size_t)E + slot] = atts[3 * (size_t)E + e];
}

// ---------------- gather ----------------
__global__ void gather_kernel(const int* __restrict__ esrc, const float* __restrict__ attp,
                              const int* __restrict__ rowp, const int* __restrict__ deg,
                              const float* __restrict__ out, float* __restrict__ agg) {
    int t = blockIdx.x * 256 + threadIdx.x;
    int n = t >> 5;
    if (n >= N) return;
    int c4 = t & 31;
    int f = c4 >> 3;
    int beg = rowp[n];
    int cnt = deg[n];
    const float* ap = attp + (size_t)f * E + beg;
    const int*   sp = esrc + beg;
    float4 acc = make_float4(0.f, 0.f, 0.f, 0.f);
    for (int i = 0; i < cnt; ++i) {
        int s = sp[i];
        float a = ap[i];
        float4 v = *(const float4*)(out + (size_t)s * DIM + c4 * 4);
        acc.x += a * v.x; acc.y += a * v.y; acc.z += a * v.z; acc.w += a * v.w;
    }
    *(float4*)(agg + (size_t)n * DIM + c4 * 4) = acc;
}

// ---------------- conv + GRU: lane = node, weights via SGPR (wave-uniform) ----------------
// block = 128 threads = 2 waves = 2 f-groups x 64 nodes; grid (ceil(N/64), 2)
__global__ __launch_bounds__(128) void update_kernel(
        const float* __restrict__ agg, float* __restrict__ out,
        const float* __restrict__ Wrel, const float* __restrict__ brel,
        const float* __restrict__ Wroot,
        const float* __restrict__ wihT, const float* __restrict__ whhT,
        const float* __restrict__ bih, const float* __restrict__ bhh, int l) {
    __shared__ float sA[128 * 33];   // agg slice, then m (relu output)
    __shared__ float sH[128 * 33];   // h slice
    int tid = threadIdx.x;
    int f = __builtin_amdgcn_readfirstlane((int)(blockIdx.y * 2) + (tid >> 6));
    int n = blockIdx.x * 64 + (tid & 63);
    int nc = n < N ? n : N - 1;
    const float* pa = agg + (size_t)nc * DIM + f * ND;
    const float* ph = out + (size_t)nc * DIM + f * ND;
    float* la = &sA[tid * 33];
    float* lh = &sH[tid * 33];
    #pragma unroll
    for (int q = 0; q < 8; ++q) {
        float4 va = *(const float4*)(pa + q * 4);
        float4 vh = *(const float4*)(ph + q * 4);
        la[q * 4 + 0] = va.x; la[q * 4 + 1] = va.y; la[q * 4 + 2] = va.z; la[q * 4 + 3] = va.w;
        lh[q * 4 + 0] = vh.x; lh[q * 4 + 1] = vh.y; lh[q * 4 + 2] = vh.z; lh[q * 4 + 3] = vh.w;
    }
    // --- conv: m = relu(a@Wrel + h@Wroot + brel) ---
    const float* wrel  = Wrel  + (size_t)(f * NL + l) * 1024;
    const float* wroot = Wroot + (size_t)(f * NL + l) * 1024;
    const float* pbr   = brel + (f * NL + l) * 32;
    {
        float m[32];
        #pragma unroll
        for (int j = 0; j < 32; ++j) m[j] = pbr[j];
        for (int k = 0; k < 32; ++k) {
            float ak = la[k], hk = lh[k];
            const float* w1 = wrel + k * 32;
            const float* w2 = wroot + k * 32;
            #pragma unroll
            for (int j = 0; j < 32; ++j) m[j] = fmaf(ak, w1[j], fmaf(hk, w2[j], m[j]));
        }
        #pragma unroll
        for (int j = 0; j < 32; ++j) la[j] = fmaxf(m[j], 0.f);   // la now holds m
    }
    // --- GRU (single pass, combined gi+gh accumulators) ---
    const float* wi  = wihT + (size_t)f * 3072;
    const float* wh  = whhT + (size_t)f * 3072;
    const float* pbi = bih + f * 96;
    const float* pbh = bhh + f * 96;
    float racc[32], zacc[32], nacc[32], hnacc[32];
    #pragma unroll
    for (int j = 0; j < 32; ++j) {
        racc[j]  = pbi[j] + pbh[j];
        zacc[j]  = pbi[32 + j] + pbh[32 + j];
        nacc[j]  = pbi[64 + j];
        hnacc[j] = pbh[64 + j];
    }
    for (int k = 0; k < 32; ++k) {
        float mk = la[k], hk = lh[k];
        const float* wik = wi + k * 96;
        const float* whk = wh + k * 96;
        #pragma unroll
        for (int j = 0; j < 32; ++j) {
            racc[j]  = fmaf(hk, whk[j],      fmaf(mk, wik[j],      racc[j]));
            zacc[j]  = fmaf(hk, whk[32 + j], fmaf(mk, wik[32 + j], zacc[j]));
            nacc[j]  = fmaf(mk, wik[64 + j], nacc[j]);
            hnacc[j] = fmaf(hk, whk[64 + j], hnacc[j]);
        }
    }
    if (n < N) {
        float res[32];
        #pragma unroll
        for (int j = 0; j < 32; ++j) {
            float r  = sigm(racc[j]);
            float z  = sigm(zacc[j]);
            float xx = nacc[j] + r * hnacc[j];
            float nn = 2.f * sigm(2.f * xx) - 1.f;   // tanh
            res[j] = (1.f - z) * nn + z * lh[j];
        }
        float* po = out + (size_t)n * DIM + f * ND;
        #pragma unroll
        for (int q = 0; q < 8; ++q)
            *(float4*)(po + q * 4) = make_float4(res[4*q], res[4*q+1], res[4*q+2], res[4*q+3]);
    }
}

// ---------------- pooling ----------------
__global__ void ghist_kernel(const int* __restrict__ batch, int* __restrict__ gcnt) {
    int n = blockIdx.x * 256 + threadIdx.x;
    if (n < N) atomicAdd(&gcnt[batch[n]], 1);
}

__global__ void gscan_kernel(const int* __restrict__ gcnt, int* __restrict__ goff) {
    __shared__ int sh[256];
    int v = gcnt[threadIdx.x];
    sh[threadIdx.x] = v;
    __syncthreads();
    for (int off = 1; off < 256; off <<= 1) {
        int t = 0;
        if ((int)threadIdx.x >= off) t = sh[threadIdx.x - off];
        __syncthreads();
        sh[threadIdx.x] += t;
        __syncthreads();
    }
    goff[threadIdx.x] = sh[threadIdx.x] - v;
}

__global__ void pool_kernel(const float* __restrict__ st, const int* __restrict__ goff,
                            const int* __restrict__ gcnt, float* __restrict__ pooled,
                            float* __restrict__ outsout) {
    __shared__ float acc2[128];
    int g = blockIdx.x;
    int c = threadIdx.x & 127;
    int half = threadIdx.x >> 7;
    int beg = goff[g], cnt = gcnt[g];
    float acc = 0.f;
    for (int i = half; i < cnt; i += 2) acc += st[(size_t)(beg + i) * DIM + c];
    if (half == 1) acc2[c] = acc;
    __syncthreads();
    if (half == 0) {
        float tot = acc + acc2[c];
        float val = tot / fmaxf((float)cnt, 1.0f);
        pooled[g * DIM + c] = val;
        int f = c >> 5, d = c & 31;
        outsout[((size_t)f * G + g) * ND + d] = val;
    }
}

__global__ void mlp_kernel(const float* __restrict__ pooled,
                           const float* __restrict__ fc1_W, const float* __restrict__ fc1_b,
                           const float* __restrict__ fc2_W, const float* __restrict__ fc2_b,
                           float* __restrict__ pred) {
    __shared__ float row[DIM], hid[DIM];
    int g = blockIdx.x, c = threadIdx.x;
    row[c] = pooled[(size_t)g * DIM + c];
    __syncthreads();
    float acc = fc1_b[c];
    #pragma unroll 8
    for (int k = 0; k < DIM; ++k) acc += row[k] * fc1_W[k * DIM + c];
    hid[c] = fmaxf(acc, 0.f);
    __syncthreads();
    if (c < NC) {
        float p = fc2_b[c];
        for (int k = 0; k < DIM; ++k) p += hid[k] * fc2_W[k * NC + c];
        pred[(size_t)g * NC + c] = p;
    }
}

extern "C" void kernel_launch(void* const* d_in, const int* in_sizes, int n_in,
                              void* d_out, int out_size, void* d_ws, size_t ws_size,
                              hipStream_t stream) {
    const float* x         = (const float*)d_in[0];
    const int*   ei        = (const int*)  d_in[1];
    const int*   batch     = (const int*)  d_in[2];
    const float* lin0_W    = (const float*)d_in[3];
    const float* lin0_b    = (const float*)d_in[4];
    const float* att_W     = (const float*)d_in[5];
    const float* att_b     = (const float*)d_in[6];
    const float* enc_W     = (const float*)d_in[7];
    const float* enc_b     = (const float*)d_in[8];
    const float* conv_Wrel = (const float*)d_in[9];
    const float* conv_brel = (const float*)d_in[10];
    const float* conv_Wroot= (const float*)d_in[11];
    const float* gru_Wih   = (const float*)d_in[12];
    const float* gru_Whh   = (const float*)d_in[13];
    const float* gru_bih   = (const float*)d_in[14];
    const float* gru_bhh   = (const float*)d_in[15];
    const float* fc1_W     = (const float*)d_in[16];
    const float* fc1_b     = (const float*)d_in[17];
    const float* fc2_W     = (const float*)d_in[18];
    const float* fc2_b     = (const float*)d_in[19];

    float* outp    = (float*)d_out;
    float* pred    = outp;                       // G*NC
    float* atts    = outp + G * NC;              // NF*E
    float* outsout = atts + (size_t)NF * E;      // NF*G*ND

    float* fp     = (float*)d_ws;
    float* st     = fp;                   fp += (size_t)N * DIM;
    float* agg    = fp;                   fp += (size_t)N * DIM;
    float* alr    = fp;                   fp += (size_t)N * 8;
    float* vl     = fp;                   fp += NF * F;
    float* vr     = fp;                   fp += NF * F;
    float* cc     = fp;                   fp += 4;
    float* pooled = fp;                   fp += G * DIM;
    float* attp   = fp;                   fp += (size_t)NF * E;
    float* wihT   = fp;                   fp += NF * 3 * ND * ND;
    float* whhT   = fp;                   fp += NF * 3 * ND * ND;
    int* ip    = (int*)fp;
    int* deg   = ip;                      ip += N;
    int* cnt   = ip;                      ip += N;   // deg & cnt adjacent -> one memset
    int* rowp  = ip;                      ip += N;
    int* bsum  = ip;                      ip += 256;
    int* gcnt  = ip;                      ip += G;
    int* goff  = ip;                      ip += G;
    int* esrc  = ip;                      ip += E;

    hipMemsetAsync(deg, 0, (size_t)(2 * N) * sizeof(int), stream);
    hipMemsetAsync(gcnt, 0, (size_t)G * sizeof(int), stream);

    prep_kernel<<<2, 256, 0, stream>>>(lin0_W, lin0_b, att_W, att_b, vl, vr, cc);
    wtrans_kernel<<<(NF * 3 * ND * ND + 255) / 256, 256, 0, stream>>>(gru_Wih, gru_Whh, wihT, whhT);
    encode_kernel<<<(N + 63) / 64, 256, 0, stream>>>(x, enc_W, enc_b, vl, vr, st, alr);
    att_kernel<<<(E + 255) / 256, 256, 0, stream>>>(ei, alr, cc, atts);

    // CSR build (once; reused by all 3 layers)
    hist_kernel<<<(E + 255) / 256, 256, 0, stream>>>(ei, deg);
    scan1_kernel<<<NB, 256, 0, stream>>>(deg, rowp, bsum);
    scan2_kernel<<<1, 256, 0, stream>>>(bsum);
    scan3_kernel<<<NB, 256, 0, stream>>>(rowp, bsum);
    fill_kernel<<<(E + 255) / 256, 256, 0, stream>>>(ei, atts, rowp, cnt, esrc, attp);

    for (int l = 0; l < NL; ++l) {
        gather_kernel<<<(N * 32 + 255) / 256, 256, 0, stream>>>(esrc, attp, rowp, deg, st, agg);
        dim3 gupd((N + 63) / 64, 2);
        update_kernel<<<gupd, 128, 0, stream>>>(agg, st, conv_Wrel, conv_brel, conv_Wroot,
                                                wihT, whhT, gru_bih, gru_bhh, l);
    }

    ghist_kernel<<<(N + 255) / 256, 256, 0, stream>>>(batch, gcnt);
    gscan_kernel<<<1, 256, 0, stream>>>(gcnt, goff);
    pool_kernel<<<G, 256, 0, stream>>>(st, goff, gcnt, pooled, outsout);
    mlp_kernel<<<G, DIM, 0, stream>>>(pooled, fc1_W, fc1_b, fc2_W, fc2_b, pred);
}